// Round 14
// baseline (80.957 us; speedup 1.0000x reference)
//
#include <hip/hip_runtime.h>
#include <math.h>

// Problem constants (reference: N=8, MA=24, DESIGN=26, RADIAL=15, SOFTENING=3, RM=5.0)
constexpr int MAC = 24;            // atoms per molecule
constexpr int DES = 26;            // sphere design points
constexpr int RAD = 15;            // radial points
constexpr int MS  = RAD * DES;     // 390 samples per atom
constexpr int MX  = MAC * MS;      // 9360 grid points per molecule
constexpr int GPB = 8;             // 32-lane groups per block (256 threads)
constexpr int PPB = 2 * GPB;       // 16 points per block (2 per group, packed)
constexpr int BPM = MX / PPB;      // 585 blocks per molecule (exact) -> n block-uniform
constexpr int STR = 28;            // inv row stride (floats): 112 B, conflict-free b128

typedef float v2f __attribute__((ext_vector_type(2)));

__device__ __forceinline__ v2f pk_fma(v2f a, v2f b, v2f c) {
    return __builtin_elementwise_fma(a, b, c);   // -> v_pk_fma_f32
}

// xor-butterfly step within each 32-lane half (bit-mode ds_swizzle)
template <int M>
__device__ __forceinline__ float xorswz(float v) {
    return __int_as_float(__builtin_amdgcn_ds_swizzle(__float_as_int(v), (M << 10) | 0x1f));
}
// DPP cross-lane permute (VALU pipe, not DS)
template <int CTRL>
__device__ __forceinline__ float dppx(float v) {
    return __int_as_float(__builtin_amdgcn_update_dpp(
        0, __float_as_int(v), CTRL, 0xf, 0xf, true));
}

// ---------------------------------------------------------------------------
// SINGLE fused kernel — no precompute dispatch, no d_ws.
// Build phase (once per block, 1 barrier):
//   inv_sh[24][28]  : 1/|ci-cj| row-major (b128-readable rows)
//   conc_sh[390]    : {r*sx, r*sy, r*sz, sw*w} — trig done ONCE here, not in
//                     the hot path (this was R12/R13's regression vs R10)
// Hot path per 32-lane group: one packed point-pair (v_pk_*), group-uniform
// ds_read_b128 for conc, wave-sync rx exchange, DPP+1-swizzle packed reduce.
// ---------------------------------------------------------------------------
__global__ __launch_bounds__(256) void becke_fused(
    const float* __restrict__ coords,   // [nmol, 24, 3]
    const float* __restrict__ sphere,   // [26, 3]
    const float* __restrict__ sw,       // [26]
    float* __restrict__ og,             // [nmol, MX, 3]
    float* __restrict__ odv,            // [nmol, MX, 24, 3]
    float* __restrict__ ow)             // [nmol, MX]
{
    __shared__ __align__(16) float  inv_sh[MAC][STR];  // 2.69 KB
    __shared__ __align__(16) float4 conc_sh[MS];       // 6.24 KB
    __shared__ v2f rxp[GPB][32];                       // 2 KB

    const int tid = threadIdx.x;
    const int b   = blockIdx.x;
    const int n   = b / BPM;                       // molecule (block-uniform)
    const int bm  = b - n * BPM;
    const float* cb = coords + n * MAC * 3;

    // ---- build inverse-distance table (576 entries / 256 thr) ----
    for (int e = tid; e < MAC * MAC; e += 256) {
        int ii = e / MAC, jj = e - ii * MAC;
        float dx = cb[ii * 3 + 0] - cb[jj * 3 + 0];
        float dy = cb[ii * 3 + 1] - cb[jj * 3 + 1];
        float dz = cb[ii * 3 + 2] - cb[jj * 3 + 2];
        float dd = fmaxf(dx * dx + dy * dy + dz * dz, 1e-24f);
        // diagonal: dd=1e-24 -> huge inv, but mu_ii = 0 * inv... rxi-rxi = 0,
        // and 0 * 1e12 = 0 -> s(0)=0.5 exactly (undone by *2 below). Safe.
        inv_sh[ii][jj] = __builtin_amdgcn_rcpf(__builtin_amdgcn_sqrtf(dd));
    }
    // ---- build conc table (390 entries / 256 thr), trig once per block ----
    for (int e = tid; e < MS; e += 256) {
        int k = e / DES, d = e - k * DES;
        // fp32 radial quadrature, half-angle closed form (validated R12/R13):
        // th/2 = (2k+1)/120 rev; r = 5 tan^2; w = (100 pi^2/3) s^5/c^7
        float h  = (float)(2 * k + 1) * (1.0f / 120.0f);
        float sn = __builtin_amdgcn_sinf(h);
        float cn = __builtin_amdgcn_cosf(h);
        float rc = __builtin_amdgcn_rcpf(cn);
        float t1 = sn * rc;
        float u  = t1 * t1;
        float r  = 5.0f * u;
        float w  = 328.98681f * u * u * t1 * rc * rc;
        conc_sh[e] = make_float4(r * sphere[d * 3 + 0],
                                 r * sphere[d * 3 + 1],
                                 r * sphere[d * 3 + 2],
                                 sw[d] * w);
    }
    __syncthreads();

    const int l   = tid & 31;
    const int grp = tid >> 5;
    const int s0  = bm * PPB + grp * 2;            // two points: s0, s0+1
    const bool act = (l < MAC);
    const int  i   = act ? l : (MAC - 1);

    const float cix = cb[i * 3 + 0];
    const float ciy = cb[i * 3 + 1];
    const float ciz = cb[i * 3 + 2];

    // lane's inv row: 6 conflict-free ds_read_b128 (immediate offsets)
    float inv[MAC];
    {
        const float4* irow = reinterpret_cast<const float4*>(&inv_sh[i][0]);
        #pragma unroll
        for (int q = 0; q < MAC / 4; ++q) {
            float4 v = irow[q];
            inv[q * 4 + 0] = v.x; inv[q * 4 + 1] = v.y;
            inv[q * 4 + 2] = v.z; inv[q * 4 + 3] = v.w;
        }
    }

    int ap[2];
    float gx[2], gy[2], gz[2], wt[2], rx[2];
    const size_t sgb = (size_t)n * MX + s0;
    float* dvp = odv + (sgb * MAC + i) * 3;        // p-stride = 72 floats

    #pragma unroll
    for (int p = 0; p < 2; ++p) {
        int sp = s0 + p;
        ap[p] = sp / MS;                           // magic-div (const 390)
        int tp = sp - ap[p] * MS;
        float4 cc = conc_sh[tp];                   // group-uniform b128 broadcast
        wt[p] = cc.w;
        const float* cap = cb + ap[p] * 3;         // L1-hot
        gx[p] = cap[0] + cc.x;
        gy[p] = cap[1] + cc.y;
        gz[p] = cap[2] + cc.z;
        float dx = gx[p] - cix;
        float dy = gy[p] - ciy;
        float dz = gz[p] - ciz;
        if (act) {
            dvp[p * MAC * 3 + 0] = dx;             // contiguous -> dwordx3
            dvp[p * MAC * 3 + 1] = dy;
            dvp[p * MAC * 3 + 2] = dz;
        }
        rx[p] = __builtin_amdgcn_sqrtf(dx * dx + dy * dy + dz * dz);
    }
    rxp[grp][l] = (v2f){rx[0], rx[1]};             // wave-synchronous exchange
    __builtin_amdgcn_wave_barrier();               // ordering only; DS in-order

    const v2f cm05 = {-0.5f, -0.5f}, c15 = {1.5f, 1.5f}, c05 = {0.5f, 0.5f};
    const v2f rxi = {rx[0], rx[1]};
    v2f prod = {1.0f, 1.0f};

    // Becke row product, diagonal included (s(0)=0.5 exactly, undone by *2)
    #pragma unroll
    for (int jj = 0; jj < MAC / 2; ++jj) {
        // b128 broadcast: {rx0(j0), rx1(j0), rx0(j1), rx1(j1)}
        float4 v4 = *reinterpret_cast<const float4*>(&rxp[grp][2 * jj]);
        const v2f iva = {inv[2 * jj],     inv[2 * jj]};
        const v2f ivb = {inv[2 * jj + 1], inv[2 * jj + 1]};
        v2f mu = (rxi - (v2f){v4.x, v4.y}) * iva;
        mu = mu * pk_fma(mu * mu, cm05, c15);      // soften 1
        mu = mu * pk_fma(mu * mu, cm05, c15);      // soften 2
        prod = prod * pk_fma(mu, cm05, c05);       // *= s
        v2f mv = (rxi - (v2f){v4.z, v4.w}) * ivb;
        mv = mv * pk_fma(mv * mv, cm05, c15);
        mv = mv * pk_fma(mv * mv, cm05, c15);
        prod = prod * pk_fma(mv, cm05, c05);
    }

    // mask pad lanes to 0, fold diagonal-undo factor 2; PACKED reduction:
    // both points reduced simultaneously (2 DPP + 1 pk_add per step)
    v2f su = prod * (act ? (v2f){2.0f, 2.0f} : (v2f){0.0f, 0.0f});
    const v2f cell = su;
    {
        v2f t;
        t.x = dppx<0xB1>(su.x);  t.y = dppx<0xB1>(su.y);  su = su + t; // ^1
        t.x = dppx<0x4E>(su.x);  t.y = dppx<0x4E>(su.y);  su = su + t; // ^2
        t.x = dppx<0x141>(su.x); t.y = dppx<0x141>(su.y); su = su + t; // ^4
        t.x = dppx<0x140>(su.x); t.y = dppx<0x140>(su.y); su = su + t; // ^8
        t.x = xorswz<16>(su.x);  t.y = xorswz<16>(su.y);  su = su + t; // ^16
    }
    if (l == ap[0])   // lane a holds cell_a; rcp ok (2% threshold slack)
        ow[sgb + 0] = cell.x * __builtin_amdgcn_rcpf(su.x) * wt[0];
    if (l == ap[1])
        ow[sgb + 1] = cell.y * __builtin_amdgcn_rcpf(su.y) * wt[1];

    if (l >= MAC && l < MAC + 2) {   // pad lanes 24..25 store grid points
        int p = l - MAC;
        float* gp = og + (sgb + p) * 3;
        gp[0] = gx[p]; gp[1] = gy[p]; gp[2] = gz[p];
    }
}

extern "C" void kernel_launch(void* const* d_in, const int* in_sizes, int n_in,
                              void* d_out, int out_size, void* d_ws, size_t ws_size,
                              hipStream_t stream) {
    // inputs: [0]=labels (unused), [1]=coords f32 [N,24,3],
    //         [2]=sphere f32 [26,3], [3]=sphere_weights f32 [26]
    const float* coords = (const float*)d_in[1];
    const float* sphere = (const float*)d_in[2];
    const float* sw     = (const float*)d_in[3];

    const int nmol = in_sizes[1] / (MAC * 3);   // 8

    float* o     = (float*)d_out;
    float* ogrid = o;                                        // [N, MX, 3]
    float* odv   = ogrid + (size_t)nmol * MX * 3;            // [N, MX, 24, 3]
    float* owt   = odv + (size_t)nmol * MX * MAC * 3;        // [N, MX]

    becke_fused<<<dim3(nmol * BPM), dim3(256), 0, stream>>>(
        coords, sphere, sw, ogrid, odv, owt);
}